// Round 6
// baseline (32.321 us; speedup 1.0000x reference)
//
#include <hip/hip_runtime.h>

// ---------------- types / helpers ----------------
typedef short bf16x8 __attribute__((ext_vector_type(8)));
typedef float f32x4  __attribute__((ext_vector_type(4)));

__device__ __forceinline__ short f2bf(float f) {
    unsigned u = __float_as_uint(f);
    unsigned r = (u + 0x7FFFu + ((u >> 16) & 1u)) >> 16;  // RNE
    return (short)r;
}

// ---------------- single fused kernel (no prep, no ws) ----------------
// out = W_pred @ [ W_x @ xnorm + b_x ; Wr_blk @ sel + b_sum ] + b_pred + xoff
// grid 512: b = bid&127, c-quarter = bid>>7 (16 cols). 512 threads = 8 waves.
// XCD note: all 4 quarters of batch b share bid%8 -> same XCD, x lines fetched once.
// Waves 0..5 each own 16 output rows; A-fragments (weights) stream from L2 with
// on-the-fly bf16 convert -- no A staging, no prep kernel, 6 barriers total.
__global__ __launch_bounds__(512) void fused_kernel(
    const float* __restrict__ x_enc,
    const int*   __restrict__ index,
    const float* __restrict__ W_query,
    const float* __restrict__ b_query,
    const float* __restrict__ W_x,
    const float* __restrict__ b_x,
    const float* __restrict__ W_prob,
    const float* __restrict__ b_prob,
    const float* __restrict__ W_ret0,  const float* __restrict__ b_ret0,
    const float* __restrict__ W_ret1,  const float* __restrict__ b_ret1,
    const float* __restrict__ W_ret2,  const float* __restrict__ b_ret2,
    const float* __restrict__ W_pred,  const float* __restrict__ b_pred,
    const float* __restrict__ RT,
    const float* __restrict__ angles,  const int* __restrict__ wires,
    const float* __restrict__ gumbel,
    float* __restrict__ out)
{
    const int bid = blockIdx.x;
    const int b = bid & 127;
    const int cbase = (bid >> 7) * 16;
    const int t = threadIdx.x;
    const int lane = t & 63;
    const int wv = t >> 6;
    const int cl = lane & 15, g = lane >> 4;

    __shared__ __align__(16) union {
        struct { float wq[3072]; float qp[3072]; } s0;  // W_query copy; q partials [32][6][16]
        short tbuf[16][200];                             // [c][k 192+pad] bf16 (t = [t1;t2])
    } u0;
    __shared__ __align__(16) short xbuf[16][520];        // [c][k 512] bf16
    __shared__ __align__(16) union {
        float qfin[96];                                  // [w6][16]
        short selbuf[16][136];                           // [c][j 128+pad] bf16
    } u1;
    __shared__ int m_sel[16];

    const float* __restrict__ xb = x_enc + (size_t)b * 32768;

    // stage W_query into LDS (float4, coalesced)
    {
        const float4* wsrc = (const float4*)W_query;
        float4* wdst = (float4*)u0.s0.wq;
        for (int L = t; L < 768; L += 512) wdst[L] = wsrc[L];
    }

    // single x pass: thread (c 0..15, sg 0..31) loads 16 rows at column c
    const int c  = t & 15;
    const int sg = t >> 4;
    const float xo = xb[511 * 64 + cbase + c];
    const float* xs = xb + (size_t)(sg * 16) * 64 + cbase + c;
    float v[16];
    #pragma unroll
    for (int i = 0; i < 16; ++i) v[i] = xs[i * 64];

    __syncthreads();   // (1) wq visible

    // fp32 q partials + bf16 xbuf writes
    {
        #pragma unroll
        for (int i = 0; i < 16; ++i) v[i] -= xo;
        const float4* wq4 = (const float4*)u0.s0.wq;     // [6][128] float4 view
        float* qp = u0.s0.qp;
        #pragma unroll
        for (int wr = 0; wr < 6; ++wr) {
            float a = 0.f;
            #pragma unroll
            for (int i4 = 0; i4 < 4; ++i4) {
                float4 w4 = wq4[wr * 128 + sg * 4 + i4];  // uniform per 16-lane group
                a += w4.x * v[i4*4+0] + w4.y * v[i4*4+1] + w4.z * v[i4*4+2] + w4.w * v[i4*4+3];
            }
            qp[sg * 96 + wr * 16 + c] = a;
        }
        short* xrow = &xbuf[c][sg * 16];
        #pragma unroll
        for (int i = 0; i < 16; i += 2) {
            unsigned lo = (unsigned short)f2bf(v[i]);
            unsigned hi = (unsigned short)f2bf(v[i+1]);
            *(unsigned*)&xrow[i] = lo | (hi << 16);
        }
    }
    __syncthreads();   // (2) qp, xbuf ready

    // q reduce over 32 sg-groups
    if (t < 96) {
        int w6 = t >> 4, cc = t & 15;
        const float* qp = u0.s0.qp;
        float s = 0.f;
        #pragma unroll
        for (int g2 = 0; g2 < 32; ++g2) s += qp[g2 * 96 + w6 * 16 + cc];
        u1.qfin[w6 * 16 + cc] = s;
    }
    __syncthreads();   // (3)

    // argmax (fp32 q path, local qbias)
    if (t < 16) {
        float qb[6];
        #pragma unroll
        for (int w = 0; w < 6; ++w) {
            float s = b_query[w];
            for (int k2 = 0; k2 < 18; ++k2) s += (wires[k2] == w) ? angles[k2] : 0.f;
            qb[w] = s;
        }
        float e[6];
        #pragma unroll
        for (int w = 0; w < 6; ++w) e[w] = cosf(u1.qfin[w * 16 + t] + qb[w]);
        int grow = (b * 64 + cbase + t) * 4;
        float best = -1e30f; int bm = 0;
        #pragma unroll
        for (int m = 0; m < 4; ++m) {
            float lg = b_prob[m];
            #pragma unroll
            for (int w = 0; w < 6; ++w) lg += W_prob[m * 6 + w] * e[w];
            lg += gumbel[grow + m];          // argmax invariant under /0.5
            if (lg > best) { best = lg; bm = m; }   // first-max like jnp.argmax
        }
        m_sel[t] = bm;
    }
    __syncthreads();   // (4) m_sel ready; qfin dead -> selbuf reusable

    // gather selected retrieval rows -> selbuf (bf16, zero-padded j>=104)
    {
        const int idxb = index[b];
        for (int L = t; L < 16 * 136; L += 512) {
            int cc = L & 15, j = L >> 4;
            short val = 0;
            if (j < 104) {
                int i, row;
                if (j < 48)      { i = 0; row = j * 2; }
                else if (j < 80) { i = 1; row = (j - 48) * 3; }
                else             { i = 2; row = (j - 80) * 4; }
                val = f2bf(RT[(size_t)i * 122880000ull + (size_t)idxb * 24576ull
                             + (size_t)m_sel[cc] * 6144ull + (size_t)row * 64ull + cbase + cc]);
            }
            u1.selbuf[cc][j] = val;
        }
    }
    __syncthreads();   // (5) selbuf ready; qp dead -> tbuf region reusable

    if (wv < 6) {
        const int arow = wv * 16 + cl;       // A row this lane supplies
        const int r0 = wv * 16 + g * 4;      // output rows this lane accumulates

        // ---- GEMM1: t1 = W_x @ xnorm (K=512), A from L2 with cvt ----
        f32x4 acc1 = {0,0,0,0};
        const float* wxr = W_x + (size_t)arow * 512 + g * 8;
        #pragma unroll 4
        for (int ks = 0; ks < 16; ++ks) {
            float4 w0 = *(const float4*)(wxr + ks * 32);
            float4 w1 = *(const float4*)(wxr + ks * 32 + 4);
            bf16x8 av;
            av[0]=f2bf(w0.x); av[1]=f2bf(w0.y); av[2]=f2bf(w0.z); av[3]=f2bf(w0.w);
            av[4]=f2bf(w1.x); av[5]=f2bf(w1.y); av[6]=f2bf(w1.z); av[7]=f2bf(w1.w);
            bf16x8 bv = *(const bf16x8*)&xbuf[cl][ks * 32 + g * 8];
            acc1 = __builtin_amdgcn_mfma_f32_16x16x32_bf16(av, bv, acc1, 0, 0, 0);
        }
        // write t1 (+b_x) into tbuf rows 0..95; D: col=cl? no -> col=lane&15, row=g*4+reg
        {
            unsigned p0, p1;
            float bx0 = b_x[r0], bx1 = b_x[r0+1], bx2 = b_x[r0+2], bx3 = b_x[r0+3];
            p0 = (unsigned short)f2bf(acc1[0] + bx0) | ((unsigned)(unsigned short)f2bf(acc1[1] + bx1) << 16);
            p1 = (unsigned short)f2bf(acc1[2] + bx2) | ((unsigned)(unsigned short)f2bf(acc1[3] + bx3) << 16);
            unsigned* dst = (unsigned*)&u0.tbuf[cl][r0];
            dst[0] = p0; dst[1] = p1;
        }

        // ---- GEMM2: t2 = Wr_blk @ sel (K=104 pad 128), A from L2 with cvt ----
        f32x4 acc2 = {0,0,0,0};
        #pragma unroll
        for (int ks = 0; ks < 4; ++ks) {
            int kk = ks * 32 + g * 8;
            bf16x8 av = {0,0,0,0,0,0,0,0};
            if (kk < 104) {
                const float* p;
                if (kk < 48)      p = W_ret0 + (size_t)arow * 48 + kk;
                else if (kk < 80) p = W_ret1 + (size_t)arow * 32 + (kk - 48);
                else              p = W_ret2 + (size_t)arow * 24 + (kk - 80);
                float4 w0 = *(const float4*)p;
                float4 w1 = *(const float4*)(p + 4);
                av[0]=f2bf(w0.x); av[1]=f2bf(w0.y); av[2]=f2bf(w0.z); av[3]=f2bf(w0.w);
                av[4]=f2bf(w1.x); av[5]=f2bf(w1.y); av[6]=f2bf(w1.z); av[7]=f2bf(w1.w);
            }
            bf16x8 bv = *(const bf16x8*)&u1.selbuf[cl][ks * 32 + g * 8];
            acc2 = __builtin_amdgcn_mfma_f32_16x16x32_bf16(av, bv, acc2, 0, 0, 0);
        }
        {
            float bs0 = b_ret0[r0]   + b_ret1[r0]   + b_ret2[r0];
            float bs1 = b_ret0[r0+1] + b_ret1[r0+1] + b_ret2[r0+1];
            float bs2 = b_ret0[r0+2] + b_ret1[r0+2] + b_ret2[r0+2];
            float bs3 = b_ret0[r0+3] + b_ret1[r0+3] + b_ret2[r0+3];
            unsigned p0 = (unsigned short)f2bf(acc2[0] + bs0) | ((unsigned)(unsigned short)f2bf(acc2[1] + bs1) << 16);
            unsigned p1 = (unsigned short)f2bf(acc2[2] + bs2) | ((unsigned)(unsigned short)f2bf(acc2[3] + bs3) << 16);
            unsigned* dst = (unsigned*)&u0.tbuf[cl][96 + r0];
            dst[0] = p0; dst[1] = p1;
        }
    }
    __syncthreads();   // (6) tbuf complete

    // ---- GEMM3: out = W_pred @ t (K=192), A from L2 with cvt ----
    if (wv < 6) {
        const int arow = wv * 16 + cl;
        const int r0 = wv * 16 + g * 4;
        f32x4 acc3 = {0,0,0,0};
        const float* wpr = W_pred + (size_t)arow * 192 + g * 8;
        #pragma unroll
        for (int ks = 0; ks < 6; ++ks) {
            float4 w0 = *(const float4*)(wpr + ks * 32);
            float4 w1 = *(const float4*)(wpr + ks * 32 + 4);
            bf16x8 av;
            av[0]=f2bf(w0.x); av[1]=f2bf(w0.y); av[2]=f2bf(w0.z); av[3]=f2bf(w0.w);
            av[4]=f2bf(w1.x); av[5]=f2bf(w1.y); av[6]=f2bf(w1.z); av[7]=f2bf(w1.w);
            bf16x8 bv = *(const bf16x8*)&u0.tbuf[cl][ks * 32 + g * 8];
            acc3 = __builtin_amdgcn_mfma_f32_16x16x32_bf16(av, bv, acc3, 0, 0, 0);
        }
        // epilogue: D layout col=lane&15, row=4*(lane>>4)+reg (m89-verified)
        float xo0 = xb[511 * 64 + cbase + cl];
        float* op = out + (size_t)b * 6144 + (size_t)r0 * 64 + cbase;
        #pragma unroll
        for (int reg = 0; reg < 4; ++reg)
            op[reg * 64 + cl] = acc3[reg] + b_pred[r0 + reg] + xo0;
    }
}

extern "C" void kernel_launch(void* const* d_in, const int* in_sizes, int n_in,
                              void* d_out, int out_size, void* d_ws, size_t ws_size,
                              hipStream_t stream) {
    (void)in_sizes; (void)n_in; (void)out_size; (void)d_ws; (void)ws_size;
    const float* x_enc   = (const float*)d_in[0];
    const int*   index   = (const int*)d_in[1];
    const float* W_query = (const float*)d_in[2];
    const float* b_query = (const float*)d_in[3];
    const float* W_x     = (const float*)d_in[4];
    const float* b_x     = (const float*)d_in[5];
    const float* W_prob  = (const float*)d_in[6];
    const float* b_prob  = (const float*)d_in[7];
    const float* W_ret0  = (const float*)d_in[8];
    const float* b_ret0  = (const float*)d_in[9];
    const float* W_ret1  = (const float*)d_in[10];
    const float* b_ret1  = (const float*)d_in[11];
    const float* W_ret2  = (const float*)d_in[12];
    const float* b_ret2  = (const float*)d_in[13];
    const float* W_pred  = (const float*)d_in[14];
    const float* b_pred  = (const float*)d_in[15];
    const float* RT      = (const float*)d_in[16];
    const float* angles  = (const float*)d_in[17];
    const int*   wires   = (const int*)d_in[18];
    const float* gumbel  = (const float*)d_in[19];
    float* out = (float*)d_out;

    fused_kernel<<<512, 512, 0, stream>>>(x_enc, index, W_query, b_query, W_x, b_x,
                                          W_prob, b_prob,
                                          W_ret0, b_ret0, W_ret1, b_ret1, W_ret2, b_ret2,
                                          W_pred, b_pred, RT, angles, wires, gumbel, out);
}

// Round 7
// 26.038 us; speedup vs baseline: 1.2413x; 1.2413x over previous
//
#include <hip/hip_runtime.h>

// ---------------- types / helpers ----------------
typedef short bf16x8 __attribute__((ext_vector_type(8)));
typedef float f32x4  __attribute__((ext_vector_type(4)));

// ws layout (floats): [0,30720) = Apack (61440 bf16 = 20 ksteps * 6144 B)
//                     [30720,30816) = cst96, [30816,30822) = qbias
#define WS_CONST 30720
#define WS_QBIAS 30816

__device__ __forceinline__ short f2bf(float f) {
    unsigned u = __float_as_uint(f);
    unsigned r = (u + 0x7FFFu + ((u >> 16) & 1u)) >> 16;  // RNE
    return (short)r;
}

// ---------------- prep: pack A = [M1 | M2] into MFMA fragment order (bf16) ----------------
// Apack layout: [kstep32 0..19][mt 0..5][lane 0..63][8 bf16]
//   elem e of lane holds M[mt*16+(lane&15)][kstep*32 + 8*(lane>>4) + e]
// ksteps 0..15: M1 = W_pred[:, :96] @ W_x  (k = s, 0..511)
// ksteps 16..19: M2 = W_pred[:, 96:] @ blockdiag(W_ret) cols (k = 512 + j, j 0..127, zero j>=104)
__global__ __launch_bounds__(256) void prep_kernel(
    const float* __restrict__ W_query, const float* __restrict__ b_query,
    const float* __restrict__ W_x,     const float* __restrict__ b_x,
    const float* __restrict__ W_ret0,  const float* __restrict__ b_ret0,
    const float* __restrict__ W_ret1,  const float* __restrict__ b_ret1,
    const float* __restrict__ W_ret2,  const float* __restrict__ b_ret2,
    const float* __restrict__ W_pred,  const float* __restrict__ b_pred,
    const float* __restrict__ angles,  const int* __restrict__ wires,
    float* __restrict__ ws)
{
    const int bid = blockIdx.x;
    const int t = threadIdx.x;
    __shared__ float wp[9216];   // W_pred half [96][96]
    __shared__ float wsl[768];   // slice [96][8]
    short* ap = (short*)ws;

    if (bid < 80) {
        const bool isM1 = bid < 64;
        for (int L = t; L < 9216; L += 256) {
            int r = L / 96, k = L - r * 96;
            wp[L] = W_pred[r * 192 + (isM1 ? k : 96 + k)];
        }
        if (isM1) {
            const int s0 = bid * 8;
            for (int L = t; L < 768; L += 256) {
                int k = L >> 3, s = L & 7;
                wsl[L] = W_x[k * 512 + s0 + s];
            }
        } else {
            const int j0 = (bid - 64) * 8;
            for (int L = t; L < 768; L += 256) {
                int k = L >> 3, jj = L & 7;
                int j = j0 + jj;
                float v = 0.f;
                if (j < 104) {
                    const float* Wr; int d, jl;
                    if (j < 48)      { Wr = W_ret0; d = 48; jl = j; }
                    else if (j < 80) { Wr = W_ret1; d = 32; jl = j - 48; }
                    else             { Wr = W_ret2; d = 24; jl = j - 80; }
                    v = Wr[k * d + jl];
                }
                wsl[L] = v;
            }
        }
        __syncthreads();
        #pragma unroll
        for (int i = 0; i < 3; ++i) {
            int idx = t + i * 256;             // 0..767
            int r = idx >> 3, s = idx & 7;
            float acc = 0.f;
            #pragma unroll 8
            for (int k = 0; k < 96; ++k) acc += wp[r * 96 + k] * wsl[k * 8 + s];
            int sg = isM1 ? (bid * 8 + s) : (512 + (bid - 64) * 8 + s);
            int kstep = sg >> 5, s32 = sg & 31;
            int g = s32 >> 3, e = s32 & 7;
            ap[kstep * 3072 + (r >> 4) * 512 + (g * 16 + (r & 15)) * 8 + e] = f2bf(acc);
        }
    } else {
        if (t < 96) {
            float v = b_pred[t];
            for (int k = 0; k < 96; ++k) {
                v += W_pred[t * 192 + k] * b_x[k];
                v += W_pred[t * 192 + 96 + k] * (b_ret0[k] + b_ret1[k] + b_ret2[k]);
            }
            ws[WS_CONST + t] = v;
        } else if (t < 102) {
            int w = t - 96;
            float v = b_query[w];
            for (int k = 0; k < 18; ++k)
                if (wires[k] == w) v += angles[k];
            ws[WS_QBIAS + w] = v;
        }
    }
}

// ---------------- main fused kernel ----------------
// grid 512: b = bid&127, c-quarter = bid>>7 (16 cols). 512 threads = 8 waves.
// XCD note: all 4 quarters of batch b share bid%8 -> same XCD, x lines fetched once.
// MFMA A-operands load DIRECTLY global->VGPR (coalesced lane*16, L2-hot Apack):
// no Abuf, no staging barriers. Waves 6..7 gather RT during waves 0..5's x-MFMA.
__global__ __launch_bounds__(512) void main_kernel(
    const float* __restrict__ x_enc,
    const int*   __restrict__ index,
    const float* __restrict__ W_query,
    const float* __restrict__ W_prob,
    const float* __restrict__ b_prob,
    const float* __restrict__ RT,
    const float* __restrict__ gumbel,
    const float* __restrict__ ws,
    float* __restrict__ out)
{
    const int bid = blockIdx.x;
    const int b = bid & 127;
    const int cbase = (bid >> 7) * 16;
    const int t = threadIdx.x;
    const int lane = t & 63;
    const int wv = t >> 6;
    const int cl = lane & 15, g = lane >> 4;

    __shared__ __align__(16) struct { float wq[3072]; float qp[3072]; } s0;
    __shared__ __align__(16) short xbuf[16][520];        // [c][k 512] bf16
    __shared__ __align__(16) union {
        float qfin[96];                                  // [w6][16]
        short selbuf[16][136];                           // [c][j 128+pad] bf16
    } u1;
    __shared__ int m_sel[16];

    const float* __restrict__ xb = x_enc + (size_t)b * 32768;

    // stage W_query into LDS (float4, coalesced)
    {
        const float4* wsrc = (const float4*)W_query;
        float4* wdst = (float4*)s0.wq;
        for (int L = t; L < 768; L += 512) wdst[L] = wsrc[L];
    }

    // single x pass: thread (c 0..15, sg 0..31) loads 16 rows at column c
    const int c  = t & 15;
    const int sg = t >> 4;
    const float xo = xb[511 * 64 + cbase + c];
    const float* xs = xb + (size_t)(sg * 16) * 64 + cbase + c;
    float v[16];
    #pragma unroll
    for (int i = 0; i < 16; ++i) v[i] = xs[i * 64];

    __syncthreads();   // (1) wq visible

    // fp32 q partials + bf16 xbuf writes
    {
        #pragma unroll
        for (int i = 0; i < 16; ++i) v[i] -= xo;
        const float4* wq4 = (const float4*)s0.wq;        // [6][128] float4 view
        float* qp = s0.qp;
        #pragma unroll
        for (int wr = 0; wr < 6; ++wr) {
            float a = 0.f;
            #pragma unroll
            for (int i4 = 0; i4 < 4; ++i4) {
                float4 w4 = wq4[wr * 128 + sg * 4 + i4];  // uniform per 16-lane group
                a += w4.x * v[i4*4+0] + w4.y * v[i4*4+1] + w4.z * v[i4*4+2] + w4.w * v[i4*4+3];
            }
            qp[sg * 96 + wr * 16 + c] = a;
        }
        short* xrow = &xbuf[c][sg * 16];
        #pragma unroll
        for (int i = 0; i < 16; i += 2) {
            unsigned lo = (unsigned short)f2bf(v[i]);
            unsigned hi = (unsigned short)f2bf(v[i+1]);
            *(unsigned*)&xrow[i] = lo | (hi << 16);
        }
    }
    __syncthreads();   // (2) qp, xbuf ready

    // q reduce over 32 sg-groups
    if (t < 96) {
        int w6 = t >> 4, cc = t & 15;
        const float* qp = s0.qp;
        float s = 0.f;
        #pragma unroll
        for (int g2 = 0; g2 < 32; ++g2) s += qp[g2 * 96 + w6 * 16 + cc];
        u1.qfin[w6 * 16 + cc] = s;
    }
    __syncthreads();   // (3)

    // argmax (fp32 q path)
    if (t < 16) {
        float e[6];
        #pragma unroll
        for (int w = 0; w < 6; ++w) e[w] = cosf(u1.qfin[w * 16 + t] + ws[WS_QBIAS + w]);
        int grow = (b * 64 + cbase + t) * 4;
        float best = -1e30f; int bm = 0;
        #pragma unroll
        for (int m = 0; m < 4; ++m) {
            float lg = b_prob[m];
            #pragma unroll
            for (int w = 0; w < 6; ++w) lg += W_prob[m * 6 + w] * e[w];
            lg += gumbel[grow + m];          // argmax invariant under /0.5
            if (lg > best) { best = lg; bm = m; }   // first-max like jnp.argmax
        }
        m_sel[t] = bm;
    }
    __syncthreads();   // (4) m_sel ready; qfin dead -> selbuf reusable

    // waves 6..7: gather RT -> selbuf (overlaps waves 0..5's x-MFMA)
    // waves 0..5: MFMA over K=512 x-part, A direct from global (coalesced, L2)
    const char* Ap = (const char*)ws;
    const char* arow_base = Ap + wv * 1024 + lane * 16;
    f32x4 acc = {0,0,0,0};
    if (wv >= 6) {
        const int t2 = t - 384;
        const int idxb = index[b];
        for (int L = t2; L < 16 * 136; L += 128) {
            int cc = L & 15, j = L >> 4;
            short val = 0;
            if (j < 104) {
                int i, row;
                if (j < 48)      { i = 0; row = j * 2; }
                else if (j < 80) { i = 1; row = (j - 48) * 3; }
                else             { i = 2; row = (j - 80) * 4; }
                val = f2bf(RT[(size_t)i * 122880000ull + (size_t)idxb * 24576ull
                             + (size_t)m_sel[cc] * 6144ull + (size_t)row * 64ull + cbase + cc]);
            }
            u1.selbuf[cc][j] = val;
        }
    } else {
        #pragma unroll 4
        for (int ks = 0; ks < 16; ++ks) {
            bf16x8 av = *(const bf16x8*)(arow_base + ks * 6144);
            bf16x8 bv = *(const bf16x8*)&xbuf[cl][ks * 32 + g * 8];
            acc = __builtin_amdgcn_mfma_f32_16x16x32_bf16(av, bv, acc, 0, 0, 0);
        }
    }
    __syncthreads();   // (5) selbuf ready

    // waves 0..5: sel-part MFMA + epilogue
    if (wv < 6) {
        #pragma unroll
        for (int ks = 0; ks < 4; ++ks) {
            bf16x8 av = *(const bf16x8*)(arow_base + (16 + ks) * 6144);
            bf16x8 bv = *(const bf16x8*)&u1.selbuf[cl][ks * 32 + g * 8];
            acc = __builtin_amdgcn_mfma_f32_16x16x32_bf16(av, bv, acc, 0, 0, 0);
        }
        // epilogue: D layout col=lane&15, row=4*(lane>>4)+reg (m89-verified)
        const float* cst = ws + WS_CONST;
        float xo0 = xb[511 * 64 + cbase + cl];
        int r0 = wv * 16 + g * 4;
        float* op = out + (size_t)b * 6144 + (size_t)r0 * 64 + cbase;
        #pragma unroll
        for (int reg = 0; reg < 4; ++reg)
            op[reg * 64 + cl] = acc[reg] + cst[r0 + reg] + xo0;
    }
}

extern "C" void kernel_launch(void* const* d_in, const int* in_sizes, int n_in,
                              void* d_out, int out_size, void* d_ws, size_t ws_size,
                              hipStream_t stream) {
    (void)in_sizes; (void)n_in; (void)out_size; (void)ws_size;
    const float* x_enc   = (const float*)d_in[0];
    const int*   index   = (const int*)d_in[1];
    const float* W_query = (const float*)d_in[2];
    const float* b_query = (const float*)d_in[3];
    const float* W_x     = (const float*)d_in[4];
    const float* b_x     = (const float*)d_in[5];
    const float* W_prob  = (const float*)d_in[6];
    const float* b_prob  = (const float*)d_in[7];
    const float* W_ret0  = (const float*)d_in[8];
    const float* b_ret0  = (const float*)d_in[9];
    const float* W_ret1  = (const float*)d_in[10];
    const float* b_ret1  = (const float*)d_in[11];
    const float* W_ret2  = (const float*)d_in[12];
    const float* b_ret2  = (const float*)d_in[13];
    const float* W_pred  = (const float*)d_in[14];
    const float* b_pred  = (const float*)d_in[15];
    const float* RT      = (const float*)d_in[16];
    const float* angles  = (const float*)d_in[17];
    const int*   wires   = (const int*)d_in[18];
    const float* gumbel  = (const float*)d_in[19];
    float* out = (float*)d_out;
    float* ws  = (float*)d_ws;

    prep_kernel<<<81, 256, 0, stream>>>(W_query, b_query, W_x, b_x,
                                        W_ret0, b_ret0, W_ret1, b_ret1, W_ret2, b_ret2,
                                        W_pred, b_pred, angles, wires, ws);
    main_kernel<<<512, 512, 0, stream>>>(x_enc, index, W_query, W_prob, b_prob,
                                         RT, gumbel, ws, out);
}